// Round 4
// baseline (119.636 us; speedup 1.0000x reference)
//
#include <hip/hip_runtime.h>

#define NB 128      // batch
#define NT 4096     // T
#define DKD 16      // d_k == d_q
#define DW 32       // d_w
#define CHUNKS 16   // T chunks: 2048 blocks -> 8 blocks/CU -> 32 waves/CU
#define TC 256      // NT / CHUNKS
#define BLK 256
#define PT 1        // t-values per thread: TC / BLK

__device__ __forceinline__ float fast_tanh(float x) {
    // tanh(x) = 1 - 2/(e^{2x}+1); exact at +/-inf limits, ~1 ulp rcp error.
    float e = __expf(2.0f * x);
    return 1.0f - 2.0f * __builtin_amdgcn_rcpf(e + 1.0f);
}

// Two fence-free kernels (rounds 1-2 proved single-kernel fusion loses: the
// per-block agent-scope fences cost 40-60us in L2 writeback/invalidate).
// Round 3 proved the remaining limiter is residency: 1024 blocks = 4/CU in
// one generation -> load and compute phases serialize. This round: 2048
// blocks = 8/CU = full 32-wave occupancy at VGPR<=64, so block generations
// interleave and HBM stays busy under compute.
//
// Kernel 1: per (batch, chunk) block. Streams key+value (prefetched up
// front; value loads stay in flight under the score loop), computes
// p = exp(score) (no max-subtract: |score| <= ||v_w||_1+|v_b| ~ 2.6 since
// tanh is bounded), writes unnormalized p, reduces (l, ctx) to workspace.
__global__ __launch_bounds__(BLK, 4) void aa_score(
    const float* __restrict__ query, const float* __restrict__ key,
    const float* __restrict__ value, const float* __restrict__ W1,
    const float* __restrict__ W2, const float* __restrict__ bias,
    const float* __restrict__ v_w, const float* __restrict__ v_b,
    float* __restrict__ attn,      // out + 2048: unnormalized p written here
    float* __restrict__ ws_l,      // [NB*CHUNKS]
    float* __restrict__ ws_ctx)    // [NB*CHUNKS*16]
{
    const int b   = blockIdx.x >> 4;            // blockIdx / CHUNKS
    const int c   = blockIdx.x & (CHUNKS - 1);
    const int tid = threadIdx.x;

    __shared__ float s_w2[DW * DKD];   // [w][d] row-major
    __shared__ float s_comb[DW];       // q_proj[w] + bias (block-uniform)
    __shared__ float s_vw[DW];
    __shared__ float s_rctx[4 * 16];   // per-wave partial ctx
    __shared__ float s_rl[4];

    // Preamble: stage W2 (128 float4) and compute q_proj + bias (32 lanes).
    if (tid < 128)
        reinterpret_cast<float4*>(s_w2)[tid] = reinterpret_cast<const float4*>(W2)[tid];
    if (tid >= 128 && tid < 128 + DW) {
        const int w = tid - 128;
        float acc = bias[0];
        const float* q  = query + b * DKD;
        const float* w1 = W1 + w * DKD;
        #pragma unroll
        for (int d = 0; d < DKD; ++d) acc = fmaf(q[d], w1[d], acc);
        s_comb[w] = acc;
        s_vw[w]   = v_w[w];
    }
    __syncthreads();

    const float vb = v_b[0];
    // One t per thread: lane i covers bytes [i*64, i*64+64) of each array —
    // wave-contiguous 4 KB per array, fully coalesced.
    const size_t tbase = (size_t)b * NT + (size_t)c * TC + (size_t)tid;
    const float4* kp = reinterpret_cast<const float4*>(key)   + tbase * 4;
    const float4* vp = reinterpret_cast<const float4*>(value) + tbase * 4;

    // Prefetch key then value: 8 global_load_dwordx4 in flight; compute on k
    // starts as soon as k returns (vmcnt(4)), v stays in flight under it.
    float4 k0 = kp[0], k1 = kp[1], k2 = kp[2], k3 = kp[3];
    float4 v0 = vp[0], v1 = vp[1], v2 = vp[2], v3 = vp[3];

    float sc = vb;

    // w-outer: each W2 row read from LDS once (broadcast, conflict-free).
    #pragma unroll 4
    for (int w = 0; w < DW; ++w) {
        const float4* wr = reinterpret_cast<const float4*>(s_w2 + w * DKD);
        const float4 w0 = wr[0], w1 = wr[1], w2 = wr[2], w3 = wr[3];
        float h = s_comb[w];
        h = fmaf(k0.x, w0.x, h); h = fmaf(k0.y, w0.y, h);
        h = fmaf(k0.z, w0.z, h); h = fmaf(k0.w, w0.w, h);
        h = fmaf(k1.x, w1.x, h); h = fmaf(k1.y, w1.y, h);
        h = fmaf(k1.z, w1.z, h); h = fmaf(k1.w, w1.w, h);
        h = fmaf(k2.x, w2.x, h); h = fmaf(k2.y, w2.y, h);
        h = fmaf(k2.z, w2.z, h); h = fmaf(k2.w, w2.w, h);
        h = fmaf(k3.x, w3.x, h); h = fmaf(k3.y, w3.y, h);
        h = fmaf(k3.z, w3.z, h); h = fmaf(k3.w, w3.w, h);
        sc = fmaf(fast_tanh(h), s_vw[w], sc);
    }

    // p = exp(score); accumulate l and ctx (value already in registers).
    const float p = __expf(sc);
    float l = p;
    float ctx[16];
    ctx[ 0] = p * v0.x; ctx[ 1] = p * v0.y; ctx[ 2] = p * v0.z; ctx[ 3] = p * v0.w;
    ctx[ 4] = p * v1.x; ctx[ 5] = p * v1.y; ctx[ 6] = p * v1.z; ctx[ 7] = p * v1.w;
    ctx[ 8] = p * v2.x; ctx[ 9] = p * v2.y; ctx[10] = p * v2.z; ctx[11] = p * v2.w;
    ctx[12] = p * v3.x; ctx[13] = p * v3.y; ctx[14] = p * v3.z; ctx[15] = p * v3.w;

    // Write unnormalized p (kernel 2 normalizes in place). 4B/lane,
    // wave-contiguous 256B — coalesced.
    attn[(size_t)b * NT + (size_t)c * TC + tid] = p;

    // Block reduction: wave shuffle-reduce, then 4 waves via LDS.
    #pragma unroll
    for (int o = 32; o > 0; o >>= 1) l += __shfl_xor(l, o);
    #pragma unroll
    for (int d = 0; d < 16; ++d) {
        #pragma unroll
        for (int o = 32; o > 0; o >>= 1) ctx[d] += __shfl_xor(ctx[d], o);
    }
    const int wave = tid >> 6;
    const int lane = tid & 63;
    if (lane == 0) {
        s_rl[wave] = l;
        #pragma unroll
        for (int d = 0; d < 16; ++d) s_rctx[wave * 16 + d] = ctx[d];
    }
    __syncthreads();
    const int slot = b * CHUNKS + c;
    if (tid < 16)
        ws_ctx[slot * 16 + tid] =
            s_rctx[tid] + s_rctx[16 + tid] + s_rctx[32 + tid] + s_rctx[48 + tid];
    if (tid == 0)
        ws_l[slot] = s_rl[0] + s_rl[1] + s_rl[2] + s_rl[3];
}

// Kernel 2: normalize attn in place by 1/L and write context. Fat blocks
// (float4/thread, 512 blocks) so launch overhead doesn't dominate; each block
// recomputes L redundantly from 16 broadcast loads (L2/L3-resident).
__global__ __launch_bounds__(BLK) void aa_finish(
    float* __restrict__ out,          // [0,2048) context, [2048,...) attn
    const float* __restrict__ ws_l,
    const float* __restrict__ ws_ctx)
{
    const int b   = blockIdx.x >> 2;            // 4 blocks per batch
    const int q   = blockIdx.x & 3;             // quarter of the row
    const int tid = threadIdx.x;

    float L = 0.0f;
    #pragma unroll
    for (int i = 0; i < CHUNKS; ++i) L += ws_l[b * CHUNKS + i];
    const float inv = 1.0f / L;

    // 4 blocks x 256 threads x float4 = 4096 floats = one batch row.
    float4* ap = reinterpret_cast<float4*>(out + NB * DKD + (size_t)b * NT) +
                 q * BLK + tid;
    float4 p = *ap;
    p.x *= inv; p.y *= inv; p.z *= inv; p.w *= inv;
    *ap = p;

    if (q == 0 && tid < DKD) {
        const float* wc = ws_ctx + b * CHUNKS * 16;
        float s = 0.0f;
        #pragma unroll
        for (int i = 0; i < CHUNKS; ++i) s += wc[i * 16 + tid];
        out[b * DKD + tid] = s * inv;
    }
}

extern "C" void kernel_launch(void* const* d_in, const int* in_sizes, int n_in,
                              void* d_out, int out_size, void* d_ws, size_t ws_size,
                              hipStream_t stream) {
    const float* query = (const float*)d_in[0];
    const float* key   = (const float*)d_in[1];
    const float* value = (const float*)d_in[2];
    const float* W1    = (const float*)d_in[3];
    const float* W2    = (const float*)d_in[4];
    const float* bias  = (const float*)d_in[5];
    const float* v_w   = (const float*)d_in[6];
    const float* v_b   = (const float*)d_in[7];
    float* out = (float*)d_out;

    float* ws_l   = (float*)d_ws;          // NB*CHUNKS floats
    float* ws_ctx = ws_l + NB * CHUNKS;    // NB*CHUNKS*16 floats

    aa_score<<<NB * CHUNKS, BLK, 0, stream>>>(
        query, key, value, W1, W2, bias, v_w, v_b,
        out + NB * DKD, ws_l, ws_ctx);
    aa_finish<<<NB * (NT / 4 / BLK), BLK, 0, stream>>>(out, ws_l, ws_ctx);
}